// Round 1
// baseline (1213.532 us; speedup 1.0000x reference)
//
#include <hip/hip_runtime.h>
#include <hip/hip_bf16.h>
#include <math.h>

#define B_  4
#define T_  4096
#define C_  1024
#define HS_ 128

// ---------------------------------------------------------------------------
// Kernel 1: QKV projection.  out = x @ [Wq|Wk|Wv],  M=B*T=16384, K=1024, N=384
// grid = M/16 blocks, block = 384 threads (thread = one output column of q/k/v)
// ---------------------------------------------------------------------------
__global__ __launch_bounds__(384) void qkv_proj_kernel(
    const float* __restrict__ x, const float* __restrict__ Wq,
    const float* __restrict__ Wk, const float* __restrict__ Wv,
    float* __restrict__ q, float* __restrict__ k, float* __restrict__ v)
{
    __shared__ float xs[16][64];   // 16 rows x 64-wide K chunk
    const int tid  = threadIdx.x;
    const int row0 = blockIdx.x * 16;
    const int m    = tid >> 7;     // 0=q, 1=k, 2=v
    const int h    = tid & 127;
    const float* __restrict__ W = (m == 0) ? Wq : (m == 1) ? Wk : Wv;

    float acc[16];
#pragma unroll
    for (int r = 0; r < 16; ++r) acc[r] = 0.f;

    for (int kc = 0; kc < C_; kc += 64) {
        __syncthreads();           // protect xs from previous iteration's readers
        if (tid < 256) {
            int r = tid >> 4, c4 = tid & 15;
            ((float4*)xs[r])[c4] =
                ((const float4*)(x + (size_t)(row0 + r) * C_ + kc))[c4];
        }
        __syncthreads();
#pragma unroll 4
        for (int kk4 = 0; kk4 < 16; ++kk4) {
            float w0 = W[(size_t)(kc + kk4 * 4 + 0) * HS_ + h];
            float w1 = W[(size_t)(kc + kk4 * 4 + 1) * HS_ + h];
            float w2 = W[(size_t)(kc + kk4 * 4 + 2) * HS_ + h];
            float w3 = W[(size_t)(kc + kk4 * 4 + 3) * HS_ + h];
#pragma unroll
            for (int r = 0; r < 16; ++r) {
                float4 xv = ((const float4*)xs[r])[kk4];   // LDS broadcast
                acc[r] = fmaf(xv.x, w0, acc[r]);
                acc[r] = fmaf(xv.y, w1, acc[r]);
                acc[r] = fmaf(xv.z, w2, acc[r]);
                acc[r] = fmaf(xv.w, w3, acc[r]);
            }
        }
    }
    float* __restrict__ outp = (m == 0) ? q : (m == 1) ? k : v;
#pragma unroll
    for (int r = 0; r < 16; ++r)
        outp[(size_t)(row0 + r) * HS_ + h] = acc[r];
}

// ---------------------------------------------------------------------------
// Kernel 2: causal flash attention, fp32.
// Q-tile = 32 queries, K-chunk = 32 keys, online softmax.
// grid = B * 64 blocks; block processes tiles (i, 127-i) -> constant 129 chunks
// block = 256 threads.
// ---------------------------------------------------------------------------
#define PAD_ 132   // padded row stride (floats) for 128-wide tiles (16B aligned)

__global__ __launch_bounds__(256) void attn_kernel(
    const float* __restrict__ q, const float* __restrict__ k,
    const float* __restrict__ v, float* __restrict__ out)
{
    __shared__ float qs[32][PAD_];
    __shared__ float ks[32][PAD_];
    __shared__ float vs[32][PAD_];
    __shared__ float sP[32][36];       // probs, padded
    __shared__ float sAlpha[32], sM[32], sL[32];

    const int tid   = threadIdx.x;
    const int b     = blockIdx.x >> 6;
    const int pairI = blockIdx.x & 63;
    const int sc = tid & 15;           // col group (cols sc, sc+16)
    const int sr = tid >> 4;           // row group (rows sr, sr+16)
    const int rg = tid >> 7;           // 0/1 for PV row halves
    const int h  = tid & 127;          // head dim for PV/out

    const float scale = 0.03125f;      // 1024^-0.5

    for (int tpass = 0; tpass < 2; ++tpass) {
        const int qt = tpass ? (127 - pairI) : pairI;
        const int qb = qt * 32;

        __syncthreads();   // previous pass fully done (incl. sL reads)

        // load Q tile (32x128) into LDS, coalesced float4
#pragma unroll
        for (int j = 0; j < 4; ++j) {
            int f = tid + 256 * j;           // 0..1023 float4s
            int row = f >> 5, c4 = f & 31;
            ((float4*)&qs[row][0])[c4] =
                ((const float4*)(q + ((size_t)(b * T_) + qb + row) * HS_))[c4];
        }
        if (tid < 32) { sM[tid] = -1e30f; sL[tid] = 0.f; }

        float o[16];
#pragma unroll
        for (int rr = 0; rr < 16; ++rr) o[rr] = 0.f;

        __syncthreads();   // qs, sM, sL ready

        for (int kc = 0; kc <= qt; ++kc) {
            const int kb = kc * 32;
            // stage K,V chunk (32x128 each)
#pragma unroll
            for (int j = 0; j < 4; ++j) {
                int f = tid + 256 * j;
                int row = f >> 5, c4 = f & 31;
                ((float4*)&ks[row][0])[c4] =
                    ((const float4*)(k + ((size_t)(b * T_) + kb + row) * HS_))[c4];
                ((float4*)&vs[row][0])[c4] =
                    ((const float4*)(v + ((size_t)(b * T_) + kb + row) * HS_))[c4];
            }
            __syncthreads();

            // scores: thread owns rows {sr, sr+16} x cols {sc, sc+16}
            float d00 = 0.f, d01 = 0.f, d10 = 0.f, d11 = 0.f;
#pragma unroll 8
            for (int c4 = 0; c4 < 32; ++c4) {
                float4 qa = ((const float4*)&qs[sr][0])[c4];
                float4 qc = ((const float4*)&qs[sr + 16][0])[c4];
                float4 ka = ((const float4*)&ks[sc][0])[c4];
                float4 kd = ((const float4*)&ks[sc + 16][0])[c4];
                d00 += qa.x * ka.x + qa.y * ka.y + qa.z * ka.z + qa.w * ka.w;
                d01 += qa.x * kd.x + qa.y * kd.y + qa.z * kd.z + qa.w * kd.w;
                d10 += qc.x * ka.x + qc.y * ka.y + qc.z * ka.z + qc.w * ka.w;
                d11 += qc.x * kd.x + qc.y * kd.y + qc.z * kd.z + qc.w * kd.w;
            }
            float s00 = d00 * scale, s01 = d01 * scale;
            float s10 = d10 * scale, s11 = d11 * scale;
            // causal mask: key index > query index -> -inf
            const int qi0 = qb + sr, qi1 = qb + sr + 16;
            const int kj0 = kb + sc, kj1 = kb + sc + 16;
            if (kj0 > qi0) s00 = -1e30f;
            if (kj1 > qi0) s01 = -1e30f;
            if (kj0 > qi1) s10 = -1e30f;
            if (kj1 > qi1) s11 = -1e30f;

            // online softmax: row reductions across the 16 sc lanes
            float mx0 = fmaxf(s00, s01), mx1 = fmaxf(s10, s11);
#pragma unroll
            for (int msk = 1; msk < 16; msk <<= 1) {
                mx0 = fmaxf(mx0, __shfl_xor(mx0, msk));
                mx1 = fmaxf(mx1, __shfl_xor(mx1, msk));
            }
            float mOld0 = sM[sr], mOld1 = sM[sr + 16];
            float mN0 = fmaxf(mOld0, mx0), mN1 = fmaxf(mOld1, mx1);
            float a0 = __expf(mOld0 - mN0), a1 = __expf(mOld1 - mN1);
            float p00 = __expf(s00 - mN0), p01 = __expf(s01 - mN0);
            float p10 = __expf(s10 - mN1), p11 = __expf(s11 - mN1);
            float rs0 = p00 + p01, rs1 = p10 + p11;
#pragma unroll
            for (int msk = 1; msk < 16; msk <<= 1) {
                rs0 += __shfl_xor(rs0, msk);
                rs1 += __shfl_xor(rs1, msk);
            }
            if (sc == 0) {
                sM[sr]      = mN0;  sM[sr + 16] = mN1;
                sL[sr]      = sL[sr]      * a0 + rs0;
                sL[sr + 16] = sL[sr + 16] * a1 + rs1;
                sAlpha[sr]      = a0;
                sAlpha[sr + 16] = a1;
            }
            sP[sr][sc]           = p00;
            sP[sr][sc + 16]      = p01;
            sP[sr + 16][sc]      = p10;
            sP[sr + 16][sc + 16] = p11;
            __syncthreads();   // sP, sAlpha ready

            // PV: thread owns column h for rows rg*16 .. rg*16+15
#pragma unroll
            for (int rr = 0; rr < 16; ++rr) o[rr] *= sAlpha[rg * 16 + rr];
#pragma unroll 2
            for (int s4 = 0; s4 < 8; ++s4) {
                float v0 = vs[s4 * 4 + 0][h];
                float v1 = vs[s4 * 4 + 1][h];
                float v2 = vs[s4 * 4 + 2][h];
                float v3 = vs[s4 * 4 + 3][h];
#pragma unroll
                for (int rr = 0; rr < 16; ++rr) {
                    float4 p4 = ((const float4*)&sP[rg * 16 + rr][0])[s4];
                    o[rr] += p4.x * v0 + p4.y * v1 + p4.z * v2 + p4.w * v3;
                }
            }
            __syncthreads();   // PV done before ks/vs restaged
        }

        // epilogue: divide by l and store (coalesced over h)
#pragma unroll
        for (int rr = 0; rr < 16; ++rr) {
            int r = rg * 16 + rr;
            float invl = 1.0f / sL[r];
            out[((size_t)(b * T_) + qb + r) * HS_ + h] = o[rr] * invl;
        }
    }
}

// ---------------------------------------------------------------------------
extern "C" void kernel_launch(void* const* d_in, const int* in_sizes, int n_in,
                              void* d_out, int out_size, void* d_ws, size_t ws_size,
                              hipStream_t stream)
{
    const float* x  = (const float*)d_in[0];
    const float* Wq = (const float*)d_in[1];
    const float* Wk = (const float*)d_in[2];
    const float* Wv = (const float*)d_in[3];
    float* out = (float*)d_out;

    const size_t M = (size_t)B_ * T_;     // 16384
    float* q = (float*)d_ws;
    float* k = q + M * HS_;
    float* v = k + M * HS_;

    qkv_proj_kernel<<<(B_ * T_) / 16, 384, 0, stream>>>(x, Wq, Wk, Wv, q, k, v);
    attn_kernel<<<B_ * 64, 256, 0, stream>>>(q, k, v, out);
}

// Round 2
// 247.585 us; speedup vs baseline: 4.9015x; 4.9015x over previous
//
#include <hip/hip_runtime.h>
#include <hip/hip_bf16.h>
#include <math.h>

typedef __attribute__((ext_vector_type(8))) short short8;
typedef __attribute__((ext_vector_type(4))) float f32x4;

#define B_  4
#define T_  4096
#define C_  1024
#define HS_ 128
#define M_  (B_*T_)   // 16384

__device__ __forceinline__ unsigned short f2bf(float f) {
    unsigned int u = __float_as_uint(f);
    u = (u + 0x7FFFu + ((u >> 16) & 1u)) >> 16;   // RNE
    return (unsigned short)u;
}

// ---------------------------------------------------------------------------
// Kernel 1: W [1024][128] fp32  ->  WT bf16 [3][128][1024]  (B-frag layout)
// ---------------------------------------------------------------------------
__global__ __launch_bounds__(256) void wt_kernel(
    const float* __restrict__ Wq, const float* __restrict__ Wk,
    const float* __restrict__ Wv, unsigned short* __restrict__ WT3)
{
    int id = blockIdx.x * 256 + threadIdx.x;   // 0 .. 3*1024*128-1
    int h  = id & 127;
    int kk = (id >> 7) & 1023;
    int m  = id >> 17;
    const float* W = (m == 0) ? Wq : (m == 1) ? Wk : Wv;
    WT3[(size_t)(m * 128 + h) * 1024 + kk] = f2bf(W[(size_t)kk * 128 + h]);
}

// ---------------------------------------------------------------------------
// Kernel 2: qkv = x @ W, bf16 MFMA.  Block: 64 rows x 128 cols, 4 waves.
// grid = (256 m-tiles, 3 matrices)
// ---------------------------------------------------------------------------
__global__ __launch_bounds__(256, 3) void qkv_gemm(
    const float* __restrict__ x, const unsigned short* __restrict__ WT3,
    unsigned short* __restrict__ q, unsigned short* __restrict__ k,
    unsigned short* __restrict__ v)
{
    __shared__ unsigned short sA[64 * 72];    // [m][k] bf16
    __shared__ unsigned short sB[128 * 72];   // [n][k] bf16
    const int tid  = threadIdx.x;
    const int mt   = blockIdx.x;
    const int mm   = blockIdx.y;
    const int t0   = mt * 64;
    const int wid  = tid >> 6, lane = tid & 63;
    const int quad = lane >> 4, l15 = lane & 15;

    f32x4 acc[8];
#pragma unroll
    for (int nt = 0; nt < 8; ++nt) acc[nt] = (f32x4)0.f;

    const unsigned short* WTm = WT3 + (size_t)mm * 128 * 1024;

    for (int kc = 0; kc < C_; kc += 64) {
        __syncthreads();
        // stage A: x fp32 -> bf16 LDS
#pragma unroll
        for (int j = 0; j < 2; ++j) {
            int c = tid + 256 * j;            // 512 chunks of 8
            int row = c >> 3, c8 = c & 7;
            const float4* src = (const float4*)(x + (size_t)(t0 + row) * C_ + kc + c8 * 8);
            float4 a = src[0], b2 = src[1];
            short8 sv;
            sv[0]=f2bf(a.x);  sv[1]=f2bf(a.y);  sv[2]=f2bf(a.z);  sv[3]=f2bf(a.w);
            sv[4]=f2bf(b2.x); sv[5]=f2bf(b2.y); sv[6]=f2bf(b2.z); sv[7]=f2bf(b2.w);
            *(short8*)&sA[row * 72 + c8 * 8] = sv;
        }
        // stage B: WT bf16 direct
#pragma unroll
        for (int j = 0; j < 4; ++j) {
            int c = tid + 256 * j;            // 1024 chunks of 8
            int row = c >> 3, c8 = c & 7;
            *(short8*)&sB[row * 72 + c8 * 8] =
                *(const short8*)(WTm + (size_t)row * 1024 + kc + c8 * 8);
        }
        __syncthreads();
        short8 af0 = *(short8*)&sA[(wid * 16 + l15) * 72 + quad * 8];
        short8 af1 = *(short8*)&sA[(wid * 16 + l15) * 72 + 32 + quad * 8];
#pragma unroll
        for (int nt = 0; nt < 8; ++nt) {
            short8 bf0 = *(short8*)&sB[(nt * 16 + l15) * 72 + quad * 8];
            short8 bf1 = *(short8*)&sB[(nt * 16 + l15) * 72 + 32 + quad * 8];
            acc[nt] = __builtin_amdgcn_mfma_f32_16x16x32_bf16(af0, bf0, acc[nt], 0, 0, 0);
            acc[nt] = __builtin_amdgcn_mfma_f32_16x16x32_bf16(af1, bf1, acc[nt], 0, 0, 0);
        }
    }
    unsigned short* outp = (mm == 0) ? q : (mm == 1) ? k : v;
#pragma unroll
    for (int nt = 0; nt < 8; ++nt)
#pragma unroll
        for (int rr = 0; rr < 4; ++rr) {
            int t = t0 + wid * 16 + quad * 4 + rr;   // C row = quad*4+reg
            int h = nt * 16 + l15;                    // C col = lane&15
            outp[(size_t)t * HS_ + h] = f2bf(acc[nt][rr]);
        }
}

// ---------------------------------------------------------------------------
// Kernel 3: v [b][t][h] bf16 -> vT [b][h][t] bf16  (64x64 LDS tiles)
// grid = 4*64*2 = 512
// ---------------------------------------------------------------------------
__global__ __launch_bounds__(256) void transpose_v(
    const unsigned short* __restrict__ v, unsigned short* __restrict__ vT)
{
    __shared__ unsigned short sT[64 * 72];
    const int tid = threadIdx.x;
    const int blk = blockIdx.x;
    const int b = blk >> 7, rem = blk & 127;
    const int tt = rem >> 1, hh = rem & 1;
#pragma unroll
    for (int j = 0; j < 2; ++j) {
        int c = tid + 256 * j;
        int r = c >> 3, c8 = c & 7;
        *(short8*)&sT[r * 72 + c8 * 8] =
            *(const short8*)(v + ((size_t)(b * T_) + tt * 64 + r) * HS_ + hh * 64 + c8 * 8);
    }
    __syncthreads();
#pragma unroll
    for (int j = 0; j < 2; ++j) {
        int c = tid + 256 * j;
        int hr = c >> 3, t8 = c & 7;
        short8 o;
#pragma unroll
        for (int i = 0; i < 8; ++i) o[i] = (short)sT[(t8 * 8 + i) * 72 + hr];
        *(short8*)(vT + ((size_t)(b * HS_) + hh * 64 + hr) * T_ + tt * 64 + t8 * 8) = o;
    }
}

// ---------------------------------------------------------------------------
// Kernel 4: causal flash attention, bf16 MFMA.
// Q-tile = 16 rows (shared by 4 waves); per iter 128 keys split 4-way by wave.
// Pairing (p, 255-p) -> 512 blocks x 33 uniform chunk-iterations.
// ---------------------------------------------------------------------------
#define SKP 136   // sK/sV row stride (bf16 elems)
#define SPP 40    // sP row stride

__global__ __launch_bounds__(256, 2) void attn_mfma(
    const unsigned short* __restrict__ q, const unsigned short* __restrict__ k,
    const unsigned short* __restrict__ vT, float* __restrict__ out)
{
    __shared__ __align__(16) unsigned char smem[
        (128 * SKP + 128 * SKP + 4 * 16 * SPP) * 2 + (64 + 64 + 16) * 4];
    unsigned short* sK = (unsigned short*)smem;          // [key][h]   128x136
    unsigned short* sV = sK + 128 * SKP;                 // [h][key]   128x136
    unsigned short* sP = sV + 128 * SKP;                 // [wave][16][40]
    float* sRedM = (float*)(sP + 4 * 16 * SPP);          // [4][16]
    float* sRedS = sRedM + 64;                           // [4][16]
    float* sL    = sRedS + 64;                           // [16]
    float* sO    = (float*)sK;                           // [4][16][132] (alias)

    const int tid  = threadIdx.x;
    const int b    = blockIdx.x >> 7;
    const int p    = blockIdx.x & 127;
    const int cc   = tid >> 6;            // wave id = key sub-chunk 0..3
    const int lane = tid & 63;
    const int quad = lane >> 4, l15 = lane & 15;

    const float sc = 0.03125f * 1.44269504088896340736f;  // C^-0.5 * log2(e)

    for (int tp = 0; tp < 2; ++tp) {
        const int qt  = tp ? (255 - p) : p;
        const int qb  = qt * 16;
        const int nkc = (qt + 8) >> 3;

        // Q fragments straight from global (already A-frag layout)
        short8 qf[4];
#pragma unroll
        for (int kf = 0; kf < 4; ++kf)
            qf[kf] = *(const short8*)(q + ((size_t)(b * T_) + qb + l15) * HS_ + kf * 32 + quad * 8);

        f32x4 O[8];
#pragma unroll
        for (int nt = 0; nt < 8; ++nt) O[nt] = (f32x4)0.f;
        float mst[4], lst[4];
#pragma unroll
        for (int rr = 0; rr < 4; ++rr) { mst[rr] = -1e30f; lst[rr] = 0.f; }

        for (int kc = 0; kc < nkc; ++kc) {
            const int kb = kc * 128;
            __syncthreads();   // prior-iter LDS reads (and sO epilogue reads) done
            // stage K: 128 keys x 128 h
#pragma unroll
            for (int j = 0; j < 8; ++j) {
                int c = tid + 256 * j;          // 2048 chunks
                int row = c >> 4, c16 = c & 15;
                *(short8*)&sK[row * SKP + c16 * 8] =
                    *(const short8*)(k + ((size_t)(b * T_) + kb + row) * HS_ + c16 * 8);
            }
            // stage V^T: 128 h x 128 keys
#pragma unroll
            for (int j = 0; j < 8; ++j) {
                int c = tid + 256 * j;
                int row = c >> 4, c16 = c & 15;
                *(short8*)&sV[row * SKP + c16 * 8] =
                    *(const short8*)(vT + ((size_t)(b * HS_) + row) * T_ + kb + c16 * 8);
            }
            __syncthreads();

            // QK^T over this wave's 32 keys
            f32x4 S[2];
            S[0] = (f32x4)0.f; S[1] = (f32x4)0.f;
#pragma unroll
            for (int nt = 0; nt < 2; ++nt)
#pragma unroll
                for (int kf = 0; kf < 4; ++kf) {
                    short8 bf = *(short8*)&sK[(cc * 32 + nt * 16 + l15) * SKP + kf * 32 + quad * 8];
                    S[nt] = __builtin_amdgcn_mfma_f32_16x16x32_bf16(qf[kf], bf, S[nt], 0, 0, 0);
                }
            // mask + scale into log2 domain
            float s[2][4];
#pragma unroll
            for (int nt = 0; nt < 2; ++nt)
#pragma unroll
                for (int rr = 0; rr < 4; ++rr) {
                    int qi = qb + quad * 4 + rr;
                    int kj = kb + cc * 32 + nt * 16 + l15;
                    s[nt][rr] = (kj > qi) ? -1e30f : S[nt][rr] * sc;
                }
            // local row max (16-lane butterfly; quads own distinct rows)
            float mloc[4];
#pragma unroll
            for (int rr = 0; rr < 4; ++rr) {
                float m = fmaxf(s[0][rr], s[1][rr]);
#pragma unroll
                for (int msk = 1; msk < 16; msk <<= 1)
                    m = fmaxf(m, __shfl_xor(m, msk));
                mloc[rr] = m;
            }
            if (l15 == 0)
#pragma unroll
                for (int rr = 0; rr < 4; ++rr)
                    sRedM[cc * 16 + quad * 4 + rr] = mloc[rr];
            __syncthreads();
            float mN[4], alpha[4];
#pragma unroll
            for (int rr = 0; rr < 4; ++rr) {
                int row = quad * 4 + rr;
                float m = fmaxf(fmaxf(sRedM[row], sRedM[16 + row]),
                                fmaxf(sRedM[32 + row], sRedM[48 + row]));
                m = fmaxf(m, mst[rr]);
                alpha[rr] = exp2f(mst[rr] - m);
                mN[rr] = m;
            }
            // p, write P (bf16, own-wave region: no barrier needed), local sums
            float rs[4] = {0.f, 0.f, 0.f, 0.f};
#pragma unroll
            for (int nt = 0; nt < 2; ++nt)
#pragma unroll
                for (int rr = 0; rr < 4; ++rr) {
                    float pv = exp2f(s[nt][rr] - mN[rr]);
                    rs[rr] += pv;
                    sP[cc * 16 * SPP + (quad * 4 + rr) * SPP + nt * 16 + l15] = f2bf(pv);
                }
#pragma unroll
            for (int rr = 0; rr < 4; ++rr) {
                float r = rs[rr];
#pragma unroll
                for (int msk = 1; msk < 16; msk <<= 1)
                    r += __shfl_xor(r, msk);
                rs[rr] = r;
            }
            if (l15 == 0)
#pragma unroll
                for (int rr = 0; rr < 4; ++rr)
                    sRedS[cc * 16 + quad * 4 + rr] = rs[rr];
            __syncthreads();
#pragma unroll
            for (int rr = 0; rr < 4; ++rr) {
                int row = quad * 4 + rr;
                float tot = sRedS[row] + sRedS[16 + row] + sRedS[32 + row] + sRedS[48 + row];
                lst[rr] = lst[rr] * alpha[rr] + tot;
                mst[rr] = mN[rr];
            }
            // rescale O, then PV
#pragma unroll
            for (int nt = 0; nt < 8; ++nt)
#pragma unroll
                for (int rr = 0; rr < 4; ++rr)
                    O[nt][rr] *= alpha[rr];
            short8 pf = *(short8*)&sP[cc * 16 * SPP + l15 * SPP + quad * 8];  // A-frag
#pragma unroll
            for (int nt = 0; nt < 8; ++nt) {
                short8 vf = *(short8*)&sV[(nt * 16 + l15) * SKP + cc * 32 + quad * 8];
                O[nt] = __builtin_amdgcn_mfma_f32_16x16x32_bf16(pf, vf, O[nt], 0, 0, 0);
            }
        }
        // ---- epilogue: combine 4 key-split partials, divide by l, store ----
        if (cc == 0 && l15 == 0)
#pragma unroll
            for (int rr = 0; rr < 4; ++rr)
                sL[quad * 4 + rr] = lst[rr];          // identical across waves
        __syncthreads();    // PV reads of sV/sK done; sO region free; sL ready
#pragma unroll
        for (int nt = 0; nt < 8; ++nt)
#pragma unroll
            for (int rr = 0; rr < 4; ++rr)
                sO[cc * 16 * 132 + (quad * 4 + rr) * 132 + nt * 16 + l15] = O[nt][rr];
        __syncthreads();
#pragma unroll
        for (int it = 0; it < 8; ++it) {
            int row = cc * 4 + (it >> 1);
            int col = (it & 1) * 64 + lane;
            float vsum = sO[row * 132 + col] + sO[16 * 132 + row * 132 + col]
                       + sO[32 * 132 + row * 132 + col] + sO[48 * 132 + row * 132 + col];
            out[((size_t)(b * T_) + qb + row) * HS_ + col] = vsum / sL[row];
        }
        // next tile's first loop-top __syncthreads protects sO reads
    }
}

// ---------------------------------------------------------------------------
extern "C" void kernel_launch(void* const* d_in, const int* in_sizes, int n_in,
                              void* d_out, int out_size, void* d_ws, size_t ws_size,
                              hipStream_t stream)
{
    const float* x  = (const float*)d_in[0];
    const float* Wq = (const float*)d_in[1];
    const float* Wk = (const float*)d_in[2];
    const float* Wv = (const float*)d_in[3];
    float* out = (float*)d_out;

    unsigned short* WT3 = (unsigned short*)d_ws;          // 3*128*1024
    unsigned short* q   = WT3 + 3 * 128 * 1024;           // M x 128
    unsigned short* k   = q + (size_t)M_ * HS_;
    unsigned short* v   = k + (size_t)M_ * HS_;
    unsigned short* vT  = v + (size_t)M_ * HS_;           // [B][128][T]

    wt_kernel<<<1536, 256, 0, stream>>>(Wq, Wk, Wv, WT3);
    qkv_gemm<<<dim3(256, 3), 256, 0, stream>>>(x, WT3, q, k, v);
    transpose_v<<<512, 256, 0, stream>>>(v, vT);
    attn_mfma<<<512, 256, 0, stream>>>(q, k, vT, out);
}